// Round 11
// baseline (142.410 us; speedup 1.0000x reference)
//
#include <hip/hip_runtime.h>

#define ROI 31
#define HALF 15
#define H_DIM 256
#define W_DIM 256
#define C_DIM 32
#define NBKT 4096               // (b<<8)|y buckets
#define VROWS (H_DIM + 2*HALF)  // 286 strip rows per image (incl. virtual OOB rows)

typedef float vfloat4 __attribute__((ext_vector_type(4)));

// Single-block counting sort by key=(b<<8)|y. Wave-shuffle scan (4 barriers).
// Outputs packed records sorted[pos]=(n<<16)|(y<<8)|x and bucket offsets off[].
__global__ __launch_bounds__(1024) void sort_kernel(
    const int* __restrict__ centers, int* __restrict__ sorted,
    int* __restrict__ off, int N)
{
    __shared__ int hist[NBKT];   // histogram, then reused as scatter cursor
    __shared__ int woff[16];     // per-wave offsets
    const int t = threadIdx.x;
    const int lane = t & 63, w = t >> 6;

    for (int k = t; k < NBKT; k += 1024) hist[k] = 0;
    __syncthreads();

    for (int i = t; i < N; i += 1024) {
        const int key = (centers[3 * i] << 8) | centers[3 * i + 1];
        atomicAdd(&hist[key], 1);
    }
    __syncthreads();

    // 4 consecutive buckets per thread; scan thread-sums wave-wide via shuffles
    const int s0 = hist[4 * t], s1 = hist[4 * t + 1];
    const int s2 = hist[4 * t + 2], s3 = hist[4 * t + 3];
    const int loc = s0 + s1 + s2 + s3;
    int incl = loc;
    #pragma unroll
    for (int d = 1; d < 64; d <<= 1) {
        int v = __shfl_up(incl, d, 64);
        if (lane >= d) incl += v;
    }
    if (lane == 63) woff[w] = incl;
    __syncthreads();
    if (w == 0) {
        const int v0 = (lane < 16) ? woff[lane] : 0;
        int v = v0;
        #pragma unroll
        for (int d = 1; d < 16; d <<= 1) {
            int u = __shfl_up(v, d, 64);
            if (lane >= d) v += u;
        }
        if (lane < 16) woff[lane] = v - v0;   // exclusive wave offset
    }
    __syncthreads();
    const int ex = woff[w] + incl - loc;      // exclusive base of bucket 4t

    hist[4 * t]     = ex;                     // hist becomes the scatter cursor
    hist[4 * t + 1] = ex + s0;
    hist[4 * t + 2] = ex + s0 + s1;
    hist[4 * t + 3] = ex + s0 + s1 + s2;
    off[4 * t]      = ex;
    off[4 * t + 1]  = ex + s0;
    off[4 * t + 2]  = ex + s0 + s1;
    off[4 * t + 3]  = ex + s0 + s1 + s2;
    if (t == 0) off[NBKT] = N;
    __syncthreads();

    for (int i = t; i < N; i += 1024) {
        const int b = centers[3 * i], y = centers[3 * i + 1], x = centers[3 * i + 2];
        const int key = (b << 8) | y;
        const int pos = atomicAdd(&hist[key], 1);
        sorted[pos] = (i << 16) | (y << 8) | x;   // packed record
    }
}

// One block per (image, virtual row rr in [-15,270]). Real rows stage 32 KB
// in LDS (each input line fetched from HBM exactly once globally) and serve
// all ROI output rows sourced from them; virtual rows store zeros to the
// rows they own. Records broadcast from a VGPR via readlane.
__global__ __launch_bounds__(256) void strip_scatter_kernel(
    const float* __restrict__ poses, const int* __restrict__ sorted,
    const int* __restrict__ off, float* __restrict__ out, int N)
{
    __shared__ vfloat4 row_lds[W_DIM * C_DIM / 4];   // 32 KB

    const int strip = blockIdx.x;
    const int b  = strip / VROWS;
    const int rr = strip % VROWS - HALF;             // -15 .. 270
    const int t  = threadIdx.x;
    const bool real = ((unsigned)rr < (unsigned)H_DIM);

    if (real) {
        const vfloat4* src_row = reinterpret_cast<const vfloat4*>(
            poses + ((size_t)b * H_DIM + rr) * W_DIM * C_DIM);
        #pragma unroll
        for (int i = 0; i < 8; ++i)
            row_lds[i * 256 + t] = src_row[i * 256 + t];
    }

    // ROIs whose window covers rr: y in [rr-15, rr+15] ∩ [0, H)
    const int ylo = max(rr - HALF, 0), yhi = min(rr + HALF, H_DIM - 1);
    const int start = off[(b << 8) | ylo];
    const int end   = off[((b << 8) | yhi) + 1];
    const int cnt   = end - start;

    // per-wave: lane l holds record start+l (clamped; excess lanes unused)
    const int lane = t & 63;
    const int recv = sorted[min(start + lane, N - 1)];

    if (real) __syncthreads();

    const int pc = t >> 3;          // output column 0..30
    const int q  = t & 7;           // float4 quad within pixel
    if (pc >= ROI) return;          // 248 active lanes

    const int m = min(cnt, 64);
    for (int j = 0; j < m; ++j) {
        const int rec = __builtin_amdgcn_readlane(recv, j);   // uniform, no mem
        const int n = rec >> 16;
        const int y = (rec >> 8) & 255;
        const int x = rec & 255;
        const int r  = rr - y + HALF;        // output row 0..30 by construction
        const int cc = x - HALF + pc;        // source column for output col pc
        vfloat4 v = (vfloat4)0.0f;
        if (real && cc >= 0 && cc < W_DIM)
            v = row_lds[cc * 8 + q];
        vfloat4* dst = reinterpret_cast<vfloat4*>(
            out + (((size_t)n * ROI + r) * ROI + pc) * C_DIM + q * 4);
        *dst = v;                            // plain store (A/B vs NT)
    }
    // rare tail: more than 64 ROIs on one strip
    for (int j = 64; j < cnt; ++j) {
        const int rec = sorted[start + j];
        const int n = rec >> 16;
        const int y = (rec >> 8) & 255;
        const int x = rec & 255;
        const int r  = rr - y + HALF;
        const int cc = x - HALF + pc;
        vfloat4 v = (vfloat4)0.0f;
        if (real && cc >= 0 && cc < W_DIM)
            v = row_lds[cc * 8 + q];
        vfloat4* dst = reinterpret_cast<vfloat4*>(
            out + (((size_t)n * ROI + r) * ROI + pc) * C_DIM + q * 4);
        *dst = v;
    }
}

extern "C" void kernel_launch(void* const* d_in, const int* in_sizes, int n_in,
                              void* d_out, int out_size, void* d_ws, size_t ws_size,
                              hipStream_t stream) {
    const float* poses   = (const float*)d_in[0];
    const int*   centers = (const int*)d_in[1];
    float*       out     = (float*)d_out;

    const int N = in_sizes[1] / 3;
    const int B = in_sizes[0] / (H_DIM * W_DIM * C_DIM);

    int* sorted = (int*)d_ws;        // N ints
    int* off    = sorted + N;        // NBKT+1 ints

    sort_kernel<<<dim3(1), dim3(1024), 0, stream>>>(centers, sorted, off, N);
    strip_scatter_kernel<<<dim3(B * VROWS), dim3(256), 0, stream>>>(poses, sorted, off, out, N);
}

// Round 12
// 113.441 us; speedup vs baseline: 1.2554x; 1.2554x over previous
//
#include <hip/hip_runtime.h>

#define ROI 31
#define HALF 15
#define H_DIM 256
#define W_DIM 256
#define C_DIM 32
#define NBKT 4096               // (b<<8)|y buckets
#define VROWS (H_DIM + 2*HALF)  // 286 strip rows per image (incl. virtual OOB rows)

typedef float vfloat4 __attribute__((ext_vector_type(4)));

// Single-block counting sort by key=(b<<8)|y.
// Outputs packed records sorted[pos]=(n<<16)|(y<<8)|x and bucket offsets off[].
__global__ __launch_bounds__(1024) void sort_kernel(
    const int* __restrict__ centers, int* __restrict__ sorted,
    int* __restrict__ off, int N)
{
    __shared__ int hist[NBKT];     // 16 KB
    __shared__ int base[NBKT];     // 16 KB
    __shared__ int partial[1024];  // 4 KB
    const int t = threadIdx.x;

    for (int k = t; k < NBKT; k += 1024) hist[k] = 0;
    __syncthreads();

    for (int i = t; i < N; i += 1024) {
        const int key = (centers[3 * i] << 8) | centers[3 * i + 1];
        atomicAdd(&hist[key], 1);
    }
    __syncthreads();

    const int s0 = hist[4 * t], s1 = hist[4 * t + 1];
    const int s2 = hist[4 * t + 2], s3 = hist[4 * t + 3];
    const int loc = s0 + s1 + s2 + s3;
    partial[t] = loc;
    __syncthreads();
    for (int o = 1; o < 1024; o <<= 1) {
        int v = (t >= o) ? partial[t - o] : 0;
        __syncthreads();
        partial[t] += v;
        __syncthreads();
    }
    const int ex = partial[t] - loc;
    base[4 * t]     = ex;
    base[4 * t + 1] = ex + s0;
    base[4 * t + 2] = ex + s0 + s1;
    base[4 * t + 3] = ex + s0 + s1 + s2;
    __syncthreads();

    for (int k = t; k < NBKT; k += 1024) off[k] = base[k];
    if (t == 0) off[NBKT] = N;
    for (int k = t; k < NBKT; k += 1024) hist[k] = 0;   // reuse as cursor
    __syncthreads();

    for (int i = t; i < N; i += 1024) {
        const int b = centers[3 * i], y = centers[3 * i + 1], x = centers[3 * i + 2];
        const int key = (b << 8) | y;
        const int pos = base[key] + atomicAdd(&hist[key], 1);
        sorted[pos] = (i << 16) | (y << 8) | x;   // packed record
    }
}

// One block per (image, virtual row rr in [-15,270]). Real rows stage 32 KB
// in LDS (each input line fetched from HBM exactly once globally) and serve
// all ROI output rows sourced from them; virtual rows store zeros to the
// rows they own. Records broadcast from a VGPR via readlane; NT stores keep
// the 504 MB output stream out of L2/L3 (load-bearing: plain stores +30 us).
__global__ __launch_bounds__(256) void strip_scatter_kernel(
    const float* __restrict__ poses, const int* __restrict__ sorted,
    const int* __restrict__ off, float* __restrict__ out, int N)
{
    __shared__ vfloat4 row_lds[W_DIM * C_DIM / 4];   // 32 KB

    const int strip = blockIdx.x;
    const int b  = strip / VROWS;
    const int rr = strip % VROWS - HALF;             // -15 .. 270
    const int t  = threadIdx.x;
    const bool real = ((unsigned)rr < (unsigned)H_DIM);

    if (real) {
        const vfloat4* src_row = reinterpret_cast<const vfloat4*>(
            poses + ((size_t)b * H_DIM + rr) * W_DIM * C_DIM);
        #pragma unroll
        for (int i = 0; i < 8; ++i)
            row_lds[i * 256 + t] = src_row[i * 256 + t];
    }

    // ROIs whose window covers rr: y in [rr-15, rr+15] ∩ [0, H)
    const int ylo = max(rr - HALF, 0), yhi = min(rr + HALF, H_DIM - 1);
    const int start = off[(b << 8) | ylo];
    const int end   = off[((b << 8) | yhi) + 1];
    const int cnt   = end - start;

    // per-wave: lane l holds record start+l (clamped; excess lanes unused)
    const int lane = t & 63;
    const int recv = sorted[min(start + lane, N - 1)];

    if (real) __syncthreads();

    const int pc = t >> 3;          // output column 0..30
    const int q  = t & 7;           // float4 quad within pixel
    if (pc >= ROI) return;          // 248 active lanes

    const int m = min(cnt, 64);
    for (int j = 0; j < m; ++j) {
        const int rec = __builtin_amdgcn_readlane(recv, j);   // uniform, no mem
        const int n = rec >> 16;
        const int y = (rec >> 8) & 255;
        const int x = rec & 255;
        const int r  = rr - y + HALF;        // output row 0..30 by construction
        const int cc = x - HALF + pc;        // source column for output col pc
        vfloat4 v = (vfloat4)0.0f;
        if (real && cc >= 0 && cc < W_DIM)
            v = row_lds[cc * 8 + q];
        float* dst = out + (((size_t)n * ROI + r) * ROI + pc) * C_DIM + q * 4;
        __builtin_nontemporal_store(v, reinterpret_cast<vfloat4*>(dst));
    }
    // rare tail: more than 64 ROIs on one strip
    for (int j = 64; j < cnt; ++j) {
        const int rec = sorted[start + j];
        const int n = rec >> 16;
        const int y = (rec >> 8) & 255;
        const int x = rec & 255;
        const int r  = rr - y + HALF;
        const int cc = x - HALF + pc;
        vfloat4 v = (vfloat4)0.0f;
        if (real && cc >= 0 && cc < W_DIM)
            v = row_lds[cc * 8 + q];
        float* dst = out + (((size_t)n * ROI + r) * ROI + pc) * C_DIM + q * 4;
        __builtin_nontemporal_store(v, reinterpret_cast<vfloat4*>(dst));
    }
}

extern "C" void kernel_launch(void* const* d_in, const int* in_sizes, int n_in,
                              void* d_out, int out_size, void* d_ws, size_t ws_size,
                              hipStream_t stream) {
    const float* poses   = (const float*)d_in[0];
    const int*   centers = (const int*)d_in[1];
    float*       out     = (float*)d_out;

    const int N = in_sizes[1] / 3;
    const int B = in_sizes[0] / (H_DIM * W_DIM * C_DIM);

    int* sorted = (int*)d_ws;        // N ints
    int* off    = sorted + N;        // NBKT+1 ints

    sort_kernel<<<dim3(1), dim3(1024), 0, stream>>>(centers, sorted, off, N);
    strip_scatter_kernel<<<dim3(B * VROWS), dim3(256), 0, stream>>>(poses, sorted, off, out, N);
}

// Round 13
// 111.923 us; speedup vs baseline: 1.2724x; 1.0136x over previous
//
#include <hip/hip_runtime.h>

#define ROI 31
#define HALF 15
#define H_DIM 256
#define W_DIM 256
#define C_DIM 32
#define NBKT 4096               // (b<<8)|y buckets
#define VROWS (H_DIM + 2*HALF)  // 286 strip rows per image (incl. virtual OOB rows)

typedef float vfloat4 __attribute__((ext_vector_type(4)));

// Single-block counting sort by key=(b<<8)|y. Wave-shuffle scan (4 barriers).
// Outputs packed records sorted[pos]=(n<<16)|(y<<8)|x and bucket offsets off[].
__global__ __launch_bounds__(1024) void sort_kernel(
    const int* __restrict__ centers, int* __restrict__ sorted,
    int* __restrict__ off, int N)
{
    __shared__ int hist[NBKT];   // histogram, then reused as scatter cursor
    __shared__ int woff[16];     // per-wave offsets
    const int t = threadIdx.x;
    const int lane = t & 63, w = t >> 6;

    for (int k = t; k < NBKT; k += 1024) hist[k] = 0;
    __syncthreads();

    for (int i = t; i < N; i += 1024) {
        const int key = (centers[3 * i] << 8) | centers[3 * i + 1];
        atomicAdd(&hist[key], 1);
    }
    __syncthreads();

    // 4 consecutive buckets per thread; scan thread-sums wave-wide via shuffles
    const int s0 = hist[4 * t], s1 = hist[4 * t + 1];
    const int s2 = hist[4 * t + 2], s3 = hist[4 * t + 3];
    const int loc = s0 + s1 + s2 + s3;
    int incl = loc;
    #pragma unroll
    for (int d = 1; d < 64; d <<= 1) {
        int v = __shfl_up(incl, d, 64);
        if (lane >= d) incl += v;
    }
    if (lane == 63) woff[w] = incl;
    __syncthreads();
    if (w == 0) {
        const int v0 = (lane < 16) ? woff[lane] : 0;
        int v = v0;
        #pragma unroll
        for (int d = 1; d < 16; d <<= 1) {
            int u = __shfl_up(v, d, 64);
            if (lane >= d) v += u;
        }
        if (lane < 16) woff[lane] = v - v0;   // exclusive wave offset
    }
    __syncthreads();
    const int ex = woff[w] + incl - loc;      // exclusive base of bucket 4t

    hist[4 * t]     = ex;                     // hist becomes the scatter cursor
    hist[4 * t + 1] = ex + s0;
    hist[4 * t + 2] = ex + s0 + s1;
    hist[4 * t + 3] = ex + s0 + s1 + s2;
    off[4 * t]      = ex;
    off[4 * t + 1]  = ex + s0;
    off[4 * t + 2]  = ex + s0 + s1;
    off[4 * t + 3]  = ex + s0 + s1 + s2;
    if (t == 0) off[NBKT] = N;
    __syncthreads();

    for (int i = t; i < N; i += 1024) {
        const int b = centers[3 * i], y = centers[3 * i + 1], x = centers[3 * i + 2];
        const int key = (b << 8) | y;
        const int pos = atomicAdd(&hist[key], 1);
        sorted[pos] = (i << 16) | (y << 8) | x;   // packed record
    }
}

// One block per (image, virtual row rr in [-15,270]). Real rows stage 32 KB
// in LDS (each input line fetched from HBM exactly once globally) and serve
// all ROI output rows sourced from them; virtual rows store zeros to the
// rows they own. Records broadcast from a VGPR via readlane; NT stores keep
// the 504 MB output stream out of L2/L3 (load-bearing: plain stores +30 us).
__global__ __launch_bounds__(256) void strip_scatter_kernel(
    const float* __restrict__ poses, const int* __restrict__ sorted,
    const int* __restrict__ off, float* __restrict__ out, int N)
{
    __shared__ vfloat4 row_lds[W_DIM * C_DIM / 4];   // 32 KB

    const int strip = blockIdx.x;
    const int b  = strip / VROWS;
    const int rr = strip % VROWS - HALF;             // -15 .. 270
    const int t  = threadIdx.x;
    const bool real = ((unsigned)rr < (unsigned)H_DIM);

    if (real) {
        const vfloat4* src_row = reinterpret_cast<const vfloat4*>(
            poses + ((size_t)b * H_DIM + rr) * W_DIM * C_DIM);
        #pragma unroll
        for (int i = 0; i < 8; ++i)
            row_lds[i * 256 + t] = src_row[i * 256 + t];
    }

    // ROIs whose window covers rr: y in [rr-15, rr+15] ∩ [0, H)
    const int ylo = max(rr - HALF, 0), yhi = min(rr + HALF, H_DIM - 1);
    const int start = off[(b << 8) | ylo];
    const int end   = off[((b << 8) | yhi) + 1];
    const int cnt   = end - start;

    // per-wave: lane l holds record start+l (clamped; excess lanes unused)
    const int lane = t & 63;
    const int recv = sorted[min(start + lane, N - 1)];

    if (real) __syncthreads();

    const int pc = t >> 3;          // output column 0..30
    const int q  = t & 7;           // float4 quad within pixel
    if (pc >= ROI) return;          // 248 active lanes

    const int m = min(cnt, 64);
    for (int j = 0; j < m; ++j) {
        const int rec = __builtin_amdgcn_readlane(recv, j);   // uniform, no mem
        const int n = rec >> 16;
        const int y = (rec >> 8) & 255;
        const int x = rec & 255;
        const int r  = rr - y + HALF;        // output row 0..30 by construction
        const int cc = x - HALF + pc;        // source column for output col pc
        vfloat4 v = (vfloat4)0.0f;
        if (real && cc >= 0 && cc < W_DIM)
            v = row_lds[cc * 8 + q];
        float* dst = out + (((size_t)n * ROI + r) * ROI + pc) * C_DIM + q * 4;
        __builtin_nontemporal_store(v, reinterpret_cast<vfloat4*>(dst));
    }
    // rare tail: more than 64 ROIs on one strip
    for (int j = 64; j < cnt; ++j) {
        const int rec = sorted[start + j];
        const int n = rec >> 16;
        const int y = (rec >> 8) & 255;
        const int x = rec & 255;
        const int r  = rr - y + HALF;
        const int cc = x - HALF + pc;
        vfloat4 v = (vfloat4)0.0f;
        if (real && cc >= 0 && cc < W_DIM)
            v = row_lds[cc * 8 + q];
        float* dst = out + (((size_t)n * ROI + r) * ROI + pc) * C_DIM + q * 4;
        __builtin_nontemporal_store(v, reinterpret_cast<vfloat4*>(dst));
    }
}

extern "C" void kernel_launch(void* const* d_in, const int* in_sizes, int n_in,
                              void* d_out, int out_size, void* d_ws, size_t ws_size,
                              hipStream_t stream) {
    const float* poses   = (const float*)d_in[0];
    const int*   centers = (const int*)d_in[1];
    float*       out     = (float*)d_out;

    const int N = in_sizes[1] / 3;
    const int B = in_sizes[0] / (H_DIM * W_DIM * C_DIM);

    int* sorted = (int*)d_ws;        // N ints
    int* off    = sorted + N;        // NBKT+1 ints

    sort_kernel<<<dim3(1), dim3(1024), 0, stream>>>(centers, sorted, off, N);
    strip_scatter_kernel<<<dim3(B * VROWS), dim3(256), 0, stream>>>(poses, sorted, off, out, N);
}